// Round 8
// baseline (494.457 us; speedup 1.0000x reference)
//
#include <hip/hip_runtime.h>
#include <hip/hip_bf16.h>
#include <stdint.h>

// Problem constants (match reference)
#define B_SZ 8
#define T_LEN 1024
#define C_DIM 1024
#define M_ROWS (B_SZ * T_LEN)   // 8192
#define NCH 32
#define CHL (T_LEN / NCH)       // 32

typedef unsigned short ushort_t;
typedef __attribute__((ext_vector_type(8))) short short8;
typedef __attribute__((ext_vector_type(4))) float f32x4;
typedef __attribute__((ext_vector_type(4))) unsigned short us4;

static __device__ __forceinline__ float bf2f(ushort_t u) {
  union { unsigned int i; float f; } x; x.i = ((unsigned int)u) << 16; return x.f;
}
static __device__ __forceinline__ ushort_t f2bf(float f) {
  union { float f; unsigned int i; } x; x.f = f;
  unsigned int r = x.i + 0x7fffu + ((x.i >> 16) & 1u);
  return (ushort_t)(r >> 16);
}

static __device__ __forceinline__ void gload_lds16(const void* g, void* l) {
  __builtin_amdgcn_global_load_lds(
      (const __attribute__((address_space(1))) void*)g,
      (__attribute__((address_space(3))) void*)l, 16, 0, 0);
}

// -------- merged weight-cvt + time-shift-mix kernel (one launch) -----------
// blocks [0, 4096): weights f32->bf16 (4M elems, 4-wide).
// blocks [4096, 12288): xm time-shift mix (8M elems, 4-wide).
__global__ void prep_kernel(const float* __restrict__ wk, const float* __restrict__ wv,
                            const float* __restrict__ wr, const float* __restrict__ wo,
                            ushort_t* __restrict__ wout,
                            const float* __restrict__ x, const float* __restrict__ tm,
                            const float* __restrict__ cm, ushort_t* __restrict__ xmb) {
  if (blockIdx.x < 4096) {
    int gid = blockIdx.x * 256 + threadIdx.x;
    int which = gid >> 18;
    int off = (gid << 2) & ((1 << 20) - 1);
    const float* src = which == 0 ? wk : which == 1 ? wv : which == 2 ? wr : wo;
    float4 v = *(const float4*)(src + off);
    us4 o = {f2bf(v.x), f2bf(v.y), f2bf(v.z), f2bf(v.w)};
    *(us4*)(wout + (size_t)gid * 4) = o;
  } else {
    int gid = (blockIdx.x - 4096) * 256 + threadIdx.x;
    int c4 = (gid & (C_DIM / 4 - 1)) * 4;
    int t = (gid >> 8) & (T_LEN - 1);
    const float4 zero = {0.f, 0.f, 0.f, 0.f};
    float4 xv = *(const float4*)(x + (size_t)gid * 4);
    float4 xp = (t > 0) ? *(const float4*)(x + (size_t)gid * 4 - C_DIM) : zero;
    float4 xn = (t < T_LEN - 1) ? *(const float4*)(x + (size_t)gid * 4 + C_DIM) : zero;
    float4 tmv = *(const float4*)(tm + c4);
    float4 cmv = *(const float4*)(cm + c4);
    float4 xc = (c4 < C_DIM / 2) ? xp : xn;
    us4 o;
    o.x = f2bf(xv.x * tmv.x + xp.x * (1.f - tmv.x) + xc.x * cmv.x);
    o.y = f2bf(xv.y * tmv.y + xp.y * (1.f - tmv.y) + xc.y * cmv.y);
    o.z = f2bf(xv.z * tmv.z + xp.z * (1.f - tmv.z) + xc.z * cmv.z);
    o.w = f2bf(xv.w * tmv.w + xp.w * (1.f - tmv.w) + xc.w * cmv.w);
    *(us4*)(xmb + (size_t)gid * 4) = o;
  }
}

// ==== fused k/v/r GEMM: 128x128, BK=32, A in LDS (3-buf), B direct-to-reg ===
// Mechanism (R7 post-mortem): old kernel was LDS-pipe-bound (48 KB LDS
// traffic per block-step vs 80 cyc MFMA). B fragments now load straight
// global->reg (weights L1/L2-hot; each row read 2x/block-step) -> LDS
// traffic halves to 24 KB, LDS shrinks to 24 KB -> 6 blocks/CU, grid 1536
// = exactly ONE round, 24 waves/CU.
// Pipeline per iter t: [load B(t+1) regs][MFMA(t): ds_read A-frags + B regs]
// [stage A(t+2), LAST vmem][vmcnt(2)][s_barrier]. vmcnt(2) guarantees
// A(t+1) landed under ANY compiler ordering (6 ops issued after it);
// B-reg RAW is compiler-guarded (normal loads). Only A(t+2) crosses barrier.
// XCD swizzle: xcd=bid&7 owns 8 contiguous bm-panels (2MB A-slice, L2-fit).
// A LDS slot swizzle (0-conflict measured): phys slot = logical^((row>>1)&3).
__global__ __launch_bounds__(256, 6) void gemm_fused(const ushort_t* __restrict__ A,
                                                     const ushort_t* __restrict__ Bw,
                                                     ushort_t* __restrict__ outK,
                                                     ushort_t* __restrict__ outV,
                                                     ushort_t* __restrict__ outR) {
  constexpr int K = 1024;
  __shared__ ushort_t As[3][128 * 32];   // 24 KB total

  const int tid = threadIdx.x;
  const int lane = tid & 63;
  const int wave = tid >> 6;

  const int bid = blockIdx.x;
  const int xcd = bid & 7;
  const int r = bid >> 3;
  const int bm = (xcd * 8 + (r & 7)) * 128;
  const int jb = r >> 3;                     // 0..23
  const int mode = jb >> 3;                  // 0:k 1:v 2:r
  const int bn = (jb & 7) * 128;
  const ushort_t* Bp = Bw + ((size_t)mode << 20);

  const int wr = (wave >> 1) * 64;
  const int wc = (wave & 1) * 64;

  f32x4 acc[4][4];
#pragma unroll
  for (int m = 0; m < 4; ++m)
#pragma unroll
    for (int n = 0; n < 4; ++n) acc[m][n] = (f32x4){0.f, 0.f, 0.f, 0.f};

  // A staging (pre-swizzled global source column)
  const int srow = tid >> 2;                         // 0..63
  const int scol = (((tid & 3) ^ ((srow >> 1) & 3)) * 8);
  const ushort_t* Ag = A + (size_t)(bm + srow) * K + scol;

  // A frag read addressing
  const int fr = lane & 15;
  const int kq = lane >> 4;
  const int ps = (kq ^ ((fr >> 1) & 3)) * 8;

  // B per-lane global base: row = bn + wc + fr, k-slot = kq*8
  const ushort_t* Bgl = Bp + (size_t)(bn + wc + fr) * K + kq * 8;

  auto stageA = [&](int buf, int kt) {
    const int k0 = kt * 32;
    ushort_t* ap = &As[buf][tid * 8];
    gload_lds16(Ag + k0, ap);
    gload_lds16(Ag + (size_t)64 * K + k0, ap + 64 * 32);
  };

  short8 b0[4], b1[4];

#define LOADB(DST, KT)                                                        \
  {                                                                           \
    _Pragma("unroll") for (int n = 0; n < 4; ++n)                             \
        DST[n] = *(const short8*)(Bgl + (size_t)n * 16 * K + (KT)*32);        \
  }

#define MFMA_STEP(ABUF, BREG)                                                 \
  {                                                                           \
    short8 af[4];                                                             \
    _Pragma("unroll") for (int m = 0; m < 4; ++m)                             \
        af[m] = *(const short8*)&As[ABUF][(wr + m * 16 + fr) * 32 + ps];      \
    _Pragma("unroll") for (int m = 0; m < 4; ++m)                             \
        _Pragma("unroll") for (int n = 0; n < 4; ++n)                         \
            acc[m][n] = __builtin_amdgcn_mfma_f32_16x16x32_bf16(              \
                af[m], BREG[n], acc[m][n], 0, 0, 0);                          \
  }

#define ENDSTEP(N)                                                            \
  asm volatile("s_waitcnt vmcnt(" #N ")" ::: "memory");                       \
  __builtin_amdgcn_s_barrier();                                               \
  __builtin_amdgcn_sched_barrier(0);

#define BODY(ACUR, ASTG, BCUR, BNXT, T)                                       \
  LOADB(BNXT, (T) + 1);                                                       \
  MFMA_STEP(ACUR, BCUR);                                                      \
  stageA(ASTG, (T) + 2);                                                      \
  ENDSTEP(2)

  // prologue: A(0)->buf0, B(0)->b0, A(1)->buf1; drain A0+B0, keep A1 flying
  stageA(0, 0);
  LOADB(b0, 0);
  stageA(1, 1);
  ENDSTEP(2)

#pragma unroll 1
  for (int i = 0; i < 5; ++i) {
    const int t0 = 6 * i;
    BODY(0, 2, b0, b1, t0 + 0)
    BODY(1, 0, b1, b0, t0 + 1)
    BODY(2, 1, b0, b1, t0 + 2)
    BODY(0, 2, b1, b0, t0 + 3)
    BODY(1, 0, b0, b1, t0 + 4)
    BODY(2, 1, b1, b0, t0 + 5)
  }
  // t=30: A buf0, b0; load B(31); no stage; full drain
  LOADB(b1, 31);
  MFMA_STEP(0, b0);
  ENDSTEP(0)
  // t=31: A buf1, b1
  MFMA_STEP(1, b1);

  // ---- epilogue: C/D layout col=lane&15, row=(lane>>4)*4+j ----
#pragma unroll
  for (int m = 0; m < 4; ++m)
#pragma unroll
    for (int n = 0; n < 4; ++n)
#pragma unroll
      for (int j = 0; j < 4; ++j) {
        float v = acc[m][n][j];
        size_t idx = (size_t)(bm + wr + m * 16 + kq * 4 + j) * C_DIM + (bn + wc + n * 16 + fr);
        if (mode == 0) {
          outK[idx] = f2bf(__expf(fminf(v, 60.f)));
        } else if (mode == 1) {
          outV[idx] = f2bf(v);
        } else {
          outR[idx] = f2bf(1.f / (1.f + __expf(-v)));
        }
      }
#undef BODY
#undef ENDSTEP
#undef MFMA_STEP
#undef LOADB
}

// ============ output GEMM: 128x128 tile, BK=64, 2-phase (R6 form) ==========
__global__ __launch_bounds__(256, 2) void gemm_out(const ushort_t* __restrict__ A,
                                                   const ushort_t* __restrict__ Bw,
                                                   float* __restrict__ outF) {
  constexpr int K = 1024;
  constexpr int NT = K / 64;
  __shared__ ushort_t As[2][128 * 64];
  __shared__ ushort_t Bs[2][128 * 64];

  const int tid = threadIdx.x;
  const int l = tid & 63;
  const int wave = tid >> 6;
  const int fr = l & 15;
  const int kq = l >> 4;

  const int bid = blockIdx.x;
  const int xcd = bid & 7;
  const int idx = bid >> 3;              // 0..63
  const int jb = idx >> 3;               // 0..7
  const int bm = (xcd * 8 + (idx & 7)) * 128;
  const int bn = jb * 128;

  const int wr = (wave >> 1) * 64;
  const int wc = (wave & 1) * 64;

  f32x4 acc[4][4];
#pragma unroll
  for (int m = 0; m < 4; ++m)
#pragma unroll
    for (int n = 0; n < 4; ++n) acc[m][n] = (f32x4){0.f, 0.f, 0.f, 0.f};

  int srow[4], scol[4];
#pragma unroll
  for (int j = 0; j < 4; ++j) {
    int row = wave * 32 + j * 8 + (l >> 3);
    srow[j] = row;
    scol[j] = ((l & 7) ^ (row & 7)) * 8;
  }
  const ushort_t* AgB = A + (size_t)bm * K;
  const ushort_t* BgB = Bw + (size_t)bn * K;
  const int dst0 = wave * 2048 + l * 8;

  auto stage = [&](int buf, int k0) {
#pragma unroll
    for (int j = 0; j < 4; ++j)
      gload_lds16(AgB + (size_t)srow[j] * K + scol[j] + k0, &As[buf][dst0 + j * 512]);
#pragma unroll
    for (int j = 0; j < 4; ++j)
      gload_lds16(BgB + (size_t)srow[j] * K + scol[j] + k0, &Bs[buf][dst0 + j * 512]);
  };

  stage(0, 0);
  asm volatile("s_waitcnt vmcnt(0)" ::: "memory");
  __syncthreads();

  const int ps0 = ((0 * 4 + kq) ^ (fr & 7)) * 8;
  const int ps1 = ((1 * 4 + kq) ^ (fr & 7)) * 8;

  int cur = 0;
  for (int t = 0; t < NT; ++t) {
    if (t < NT - 1) stage(cur ^ 1, (t + 1) * 64);
    short8 af[4][2], bfr[4][2];
#pragma unroll
    for (int m = 0; m < 4; ++m) {
      af[m][0] = *(const short8*)&As[cur][(wr + m * 16 + fr) * 64 + ps0];
      af[m][1] = *(const short8*)&As[cur][(wr + m * 16 + fr) * 64 + ps1];
    }
#pragma unroll
    for (int n = 0; n < 4; ++n) {
      bfr[n][0] = *(const short8*)&Bs[cur][(wc + n * 16 + fr) * 64 + ps0];
      bfr[n][1] = *(const short8*)&Bs[cur][(wc + n * 16 + fr) * 64 + ps1];
    }
#pragma unroll
    for (int m = 0; m < 4; ++m)
#pragma unroll
      for (int n = 0; n < 4; ++n)
#pragma unroll
        for (int ks = 0; ks < 2; ++ks)
          acc[m][n] = __builtin_amdgcn_mfma_f32_16x16x32_bf16(af[m][ks], bfr[n][ks], acc[m][n], 0, 0, 0);
    asm volatile("s_waitcnt vmcnt(0)" ::: "memory");
    __syncthreads();
    cur ^= 1;
  }

#pragma unroll
  for (int m = 0; m < 4; ++m)
#pragma unroll
    for (int n = 0; n < 4; ++n)
#pragma unroll
      for (int j = 0; j < 4; ++j)
        outF[(size_t)(bm + wr + m * 16 + kq * 4 + j) * C_DIM + (bn + wc + n * 16 + fr)] =
            acc[m][n][j];
}

// ---------------- wkv chunked scan -----------------------------------------
__global__ void wkv_phaseA(const ushort_t* __restrict__ kk, const ushort_t* __restrict__ vv,
                           const float* __restrict__ td,
                           float* __restrict__ sa, float* __restrict__ sb,
                           float* __restrict__ sp) {
  int gid = blockIdx.x * 256 + threadIdx.x;
  int c = gid & (C_DIM - 1);
  int ch = (gid >> 10) & (NCH - 1);
  int b = gid >> 15;
  float w = td[c] * (1.f / T_LEN);
  size_t base = ((size_t)b * T_LEN + ch * CHL) * C_DIM + c;
  float a = 0.f, bb = 0.f, p = -1e38f;
  for (int t = 0; t < CHL; ++t) {
    float kt = bf2f(kk[base + (size_t)t * C_DIM]);
    float vt = bf2f(vv[base + (size_t)t * C_DIM]);
    float no2 = fmaxf(w + p, kt);
    float e1 = __expf(w + p - no2);
    float e2 = __expf(kt - no2);
    a = e1 * a + e2 * vt;
    bb = e1 * bb + e2;
    p = no2;
  }
  sa[gid] = a; sb[gid] = bb; sp[gid] = p;
}

__global__ void wkv_phaseC2(const ushort_t* __restrict__ kk, const ushort_t* __restrict__ vv,
                            const ushort_t* __restrict__ sr, const float* __restrict__ td,
                            const float* __restrict__ tf,
                            const float* __restrict__ sa, const float* __restrict__ sb,
                            const float* __restrict__ sp, ushort_t* __restrict__ sy) {
  int gid = blockIdx.x * 256 + threadIdx.x;
  int c = gid & (C_DIM - 1);
  int ch = (gid >> 10) & (NCH - 1);
  int b = gid >> 15;
  float w = td[c] * (1.f / T_LEN);
  float u = tf[c] * (1.f / T_LEN);
  float wL = w * (float)CHL;

  float a = 0.f, bb = 0.f, p = -1e38f;
  size_t sbase = ((size_t)b * NCH) * C_DIM + c;
  for (int j = 0; j < ch; ++j) {
    float ac = sa[sbase + (size_t)j * C_DIM];
    float bc = sb[sbase + (size_t)j * C_DIM];
    float pc = sp[sbase + (size_t)j * C_DIM];
    float pn = fmaxf(p + wL, pc);
    float e1 = __expf(p + wL - pn);
    float e2 = __expf(pc - pn);
    a = e1 * a + e2 * ac;
    bb = e1 * bb + e2 * bc;
    p = pn;
  }

  size_t base = ((size_t)b * T_LEN + ch * CHL) * C_DIM + c;
  for (int t = 0; t < CHL; ++t) {
    float kt = bf2f(kk[base + (size_t)t * C_DIM]);
    float vt = bf2f(vv[base + (size_t)t * C_DIM]);
    float no = fmaxf(p, u + kt);
    float e1 = __expf(p - no);
    float e2 = __expf(u + kt - no);
    float y = (e1 * a + e2 * vt) / (e1 * bb + e2);
    float srv = bf2f(sr[base + (size_t)t * C_DIM]);
    sy[base + (size_t)t * C_DIM] = f2bf(srv * y);
    float no2 = fmaxf(w + p, kt);
    e1 = __expf(w + p - no2);
    e2 = __expf(kt - no2);
    a = e1 * a + e2 * vt;
    bb = e1 * bb + e2;
    p = no2;
  }
}

// ---------------------------------------------------------------------------
extern "C" void kernel_launch(void* const* d_in, const int* in_sizes, int n_in,
                              void* d_out, int out_size, void* d_ws, size_t ws_size,
                              hipStream_t stream) {
  const float* x  = (const float*)d_in[0];
  const float* td = (const float*)d_in[1];
  const float* tf = (const float*)d_in[2];
  const float* tm = (const float*)d_in[3];
  const float* cm = (const float*)d_in[4];
  const float* Wk = (const float*)d_in[5];
  const float* Wv = (const float*)d_in[6];
  const float* Wr = (const float*)d_in[7];
  const float* Wo = (const float*)d_in[8];

  const size_t MC = (size_t)M_ROWS * C_DIM;
  const size_t CC = (size_t)C_DIM * C_DIM;

  char* ws = (char*)d_ws;
  ushort_t* xmb = (ushort_t*)ws; ws += MC * 2;
  ushort_t* Wb  = (ushort_t*)ws; ws += 4 * CC * 2;
  ushort_t* kk  = (ushort_t*)ws; ws += MC * 2;
  ushort_t* vv  = (ushort_t*)ws; ws += MC * 2;
  ushort_t* sr  = (ushort_t*)ws; ws += MC * 2;
  ushort_t* sy  = (ushort_t*)ws; ws += MC * 2;
  float* sa = (float*)ws; ws += (size_t)B_SZ * NCH * C_DIM * 4;
  float* sb = (float*)ws; ws += (size_t)B_SZ * NCH * C_DIM * 4;
  float* sp = (float*)ws; ws += (size_t)B_SZ * NCH * C_DIM * 4;

  prep_kernel<<<dim3(12288), 256, 0, stream>>>(Wk, Wv, Wr, Wo, Wb, x, tm, cm, xmb);

  // fused k/v/r projections: 1536 blocks @ 6/CU (one round), B direct-to-reg
  gemm_fused<<<dim3(1536), 256, 0, stream>>>(xmb, Wb, kk, vv, sr);

  wkv_phaseA<<<(B_SZ * NCH * C_DIM) / 256, 256, 0, stream>>>(kk, vv, td, sa, sb, sp);
  wkv_phaseC2<<<(B_SZ * NCH * C_DIM) / 256, 256, 0, stream>>>(kk, vv, sr, td, tf, sa, sb, sp, sy);

  // output projection: 512 blocks, XCD-swizzled
  gemm_out<<<dim3(512), 256, 0, stream>>>(sy, Wb + 3 * CC, (float*)d_out);
}

// Round 9
// 149.002 us; speedup vs baseline: 3.3185x; 3.3185x over previous
//
#include <hip/hip_runtime.h>
#include <hip/hip_bf16.h>
#include <stdint.h>

// Problem constants (match reference)
#define B_SZ 8
#define T_LEN 1024
#define C_DIM 1024
#define M_ROWS (B_SZ * T_LEN)   // 8192
#define NCH 32
#define CHL (T_LEN / NCH)       // 32

typedef unsigned short ushort_t;
typedef __attribute__((ext_vector_type(8))) short short8;
typedef __attribute__((ext_vector_type(4))) float f32x4;
typedef __attribute__((ext_vector_type(4))) unsigned short us4;

static __device__ __forceinline__ float bf2f(ushort_t u) {
  union { unsigned int i; float f; } x; x.i = ((unsigned int)u) << 16; return x.f;
}
static __device__ __forceinline__ ushort_t f2bf(float f) {
  union { float f; unsigned int i; } x; x.f = f;
  unsigned int r = x.i + 0x7fffu + ((x.i >> 16) & 1u);
  return (ushort_t)(r >> 16);
}

static __device__ __forceinline__ void gload_lds16(const void* g, void* l) {
  __builtin_amdgcn_global_load_lds(
      (const __attribute__((address_space(1))) void*)g,
      (__attribute__((address_space(3))) void*)l, 16, 0, 0);
}

// -------- prep: Wo row-major cvt | Wk/v/r fragment-major | xm mix ----------
// Fragment-major layout for Wk/v/r (B-operand of mfma_f32_16x16x32_bf16):
//   Wf[mode][nf][kt][l][e], strides e:1, l:8, kt:512, nf:16384, mode:2^20
//   element = W[16*nf + (l&15)][32*kt + (l>>4)*8 + e]
// so a wave's LOADB of chunk(nf,kt) is 64 lanes x 16B CONTIGUOUS (1 KB).
__global__ void prep_kernel(const float* __restrict__ wk, const float* __restrict__ wv,
                            const float* __restrict__ wr, const float* __restrict__ wo,
                            ushort_t* __restrict__ wob,     // Wo row-major bf16 (1M)
                            ushort_t* __restrict__ wf,      // Wk/v/r frag-major (3M)
                            const float* __restrict__ x, const float* __restrict__ tm,
                            const float* __restrict__ cm, ushort_t* __restrict__ xmb) {
  const int bid = blockIdx.x;
  if (bid < 1024) {
    // Wo row-major f32->bf16, 4 elems/thread
    int gid = bid * 256 + threadIdx.x;
    float4 v = *(const float4*)(wo + (size_t)gid * 4);
    us4 o = {f2bf(v.x), f2bf(v.y), f2bf(v.z), f2bf(v.w)};
    *(us4*)(wob + (size_t)gid * 4) = o;
  } else if (bid < 2560) {
    // Wk/v/r fragment-major, 8 elems/thread (one lane-chunk slice)
    int g = (bid - 1024) * 256 + threadIdx.x;       // [0, 393216)
    int mode = g >> 17;
    int rem = g & 131071;
    int nf = rem >> 11;
    int rem2 = rem & 2047;
    int kt = rem2 >> 6;
    int l = rem2 & 63;
    const float* src = mode == 0 ? wk : mode == 1 ? wv : wr;
    const float* sp = src + (size_t)(nf * 16 + (l & 15)) * C_DIM + kt * 32 + (l >> 4) * 8;
    float4 v0 = *(const float4*)sp;
    float4 v1 = *(const float4*)(sp + 4);
    us4 o0 = {f2bf(v0.x), f2bf(v0.y), f2bf(v0.z), f2bf(v0.w)};
    us4 o1 = {f2bf(v1.x), f2bf(v1.y), f2bf(v1.z), f2bf(v1.w)};
    ushort_t* dst = wf + (size_t)g * 8;
    *(us4*)dst = o0;
    *(us4*)(dst + 4) = o1;
  } else {
    // xm time-shift mix, 4 elems/thread
    int gid = (bid - 2560) * 256 + threadIdx.x;
    int c4 = (gid & (C_DIM / 4 - 1)) * 4;
    int t = (gid >> 8) & (T_LEN - 1);
    const float4 zero = {0.f, 0.f, 0.f, 0.f};
    float4 xv = *(const float4*)(x + (size_t)gid * 4);
    float4 xp = (t > 0) ? *(const float4*)(x + (size_t)gid * 4 - C_DIM) : zero;
    float4 xn = (t < T_LEN - 1) ? *(const float4*)(x + (size_t)gid * 4 + C_DIM) : zero;
    float4 tmv = *(const float4*)(tm + c4);
    float4 cmv = *(const float4*)(cm + c4);
    float4 xc = (c4 < C_DIM / 2) ? xp : xn;
    us4 o;
    o.x = f2bf(xv.x * tmv.x + xp.x * (1.f - tmv.x) + xc.x * cmv.x);
    o.y = f2bf(xv.y * tmv.y + xp.y * (1.f - tmv.y) + xc.y * cmv.y);
    o.z = f2bf(xv.z * tmv.z + xp.z * (1.f - tmv.z) + xc.z * cmv.z);
    o.w = f2bf(xv.w * tmv.w + xp.w * (1.f - tmv.w) + xc.w * cmv.w);
    *(us4*)(xmb + (size_t)gid * 4) = o;
  }
}

// ==== fused k/v/r GEMM: 128x128, BK=32, A in LDS (3-buf), B frag-major ======
// R8 post-mortem fix: B global->reg loads are now COALESCED (frag-major
// pre-pack: wave reads 1KB contiguous per fragment). B never touches LDS ->
// LDS traffic per block-step 48->24 KB (the R7-measured binding pipe),
// LDS 24 KB total.
// Pipeline per window t: [LOADB B(t+1) x4][MFMA(t): ds_read A + B regs]
// [stageA(t+2) x2 gload_lds][vmcnt(6)][s_barrier]. In-flight at vmcnt:
// A(t+1)x2 (oldest), B(t+1)x4, A(t+2)x2 -> vmcnt(6) completes A(t+1).
// B-reg RAW handled by compiler-inserted waits (normal loads).
// XCD swizzle: xcd=bid&7 owns 8 contiguous bm-panels (2MB A-slice, L2-fit).
// A LDS slot swizzle (0-conflict measured): phys slot = logical^((row>>1)&3).
__global__ __launch_bounds__(256, 4) void gemm_fused(const ushort_t* __restrict__ A,
                                                     const ushort_t* __restrict__ Wf,
                                                     ushort_t* __restrict__ outK,
                                                     ushort_t* __restrict__ outV,
                                                     ushort_t* __restrict__ outR) {
  constexpr int K = 1024;
  __shared__ ushort_t As[3][128 * 32];   // 24 KB

  const int tid = threadIdx.x;
  const int lane = tid & 63;
  const int wave = tid >> 6;

  const int bid = blockIdx.x;
  const int xcd = bid & 7;
  const int r = bid >> 3;
  const int bm = (xcd * 8 + (r & 7)) * 128;
  const int jb = r >> 3;                     // 0..23
  const int mode = jb >> 3;                  // 0:k 1:v 2:r
  const int bn = (jb & 7) * 128;

  const int wr = (wave >> 1) * 64;
  const int wc = (wave & 1) * 64;

  f32x4 acc[4][4];
#pragma unroll
  for (int m = 0; m < 4; ++m)
#pragma unroll
    for (int n = 0; n < 4; ++n) acc[m][n] = (f32x4){0.f, 0.f, 0.f, 0.f};

  // A staging (pre-swizzled global source column)
  const int srow = tid >> 2;
  const int scol = (((tid & 3) ^ ((srow >> 1) & 3)) * 8);
  const ushort_t* Ag = A + (size_t)(bm + srow) * K + scol;

  // A frag read addressing
  const int fr = lane & 15;
  const int kq = lane >> 4;
  const int ps = (kq ^ ((fr >> 1) & 3)) * 8;

  // B frag-major base: chunk(nf, kt) at (nf*32 + kt)*512 elems, lane at l*8
  const ushort_t* Bgl = Wf + ((size_t)mode << 20) +
                        (size_t)((jb & 7) * 8 + (wave & 1) * 4) * 16384 + lane * 8;

  auto stageA = [&](int buf, int kt) {
    const int k0 = kt * 32;
    ushort_t* ap = &As[buf][tid * 8];
    gload_lds16(Ag + k0, ap);
    gload_lds16(Ag + (size_t)64 * K + k0, ap + 64 * 32);
  };

  short8 b0[4], b1[4];

#define LOADB(DST, KT)                                                        \
  {                                                                           \
    _Pragma("unroll") for (int n = 0; n < 4; ++n)                             \
        DST[n] = *(const short8*)(Bgl + n * 16384 + (KT)*512);                \
  }

#define MFMA_STEP(ABUF, BREG)                                                 \
  {                                                                           \
    short8 af[4];                                                             \
    _Pragma("unroll") for (int m = 0; m < 4; ++m)                             \
        af[m] = *(const short8*)&As[ABUF][(wr + m * 16 + fr) * 32 + ps];      \
    _Pragma("unroll") for (int m = 0; m < 4; ++m)                             \
        _Pragma("unroll") for (int n = 0; n < 4; ++n)                         \
            acc[m][n] = __builtin_amdgcn_mfma_f32_16x16x32_bf16(              \
                af[m], BREG[n], acc[m][n], 0, 0, 0);                          \
  }

#define ENDSTEP(N)                                                            \
  asm volatile("s_waitcnt vmcnt(" #N ")" ::: "memory");                       \
  __builtin_amdgcn_s_barrier();                                               \
  __builtin_amdgcn_sched_barrier(0);

#define BODY(ACUR, ASTG, BCUR, BNXT, T)                                       \
  LOADB(BNXT, (T) + 1);                                                       \
  MFMA_STEP(ACUR, BCUR);                                                      \
  stageA(ASTG, (T) + 2);                                                      \
  ENDSTEP(6)

  // prologue: A(0), B(0), A(1); vmcnt(2) -> A(0)+B(0) done, A(1) flying
  stageA(0, 0);
  LOADB(b0, 0);
  stageA(1, 1);
  ENDSTEP(2)

#pragma unroll 1
  for (int i = 0; i < 5; ++i) {
    const int t0 = 6 * i;
    BODY(0, 2, b0, b1, t0 + 0)
    BODY(1, 0, b1, b0, t0 + 1)
    BODY(2, 1, b0, b1, t0 + 2)
    BODY(0, 2, b1, b0, t0 + 3)
    BODY(1, 0, b0, b1, t0 + 4)
    BODY(2, 1, b1, b0, t0 + 5)
  }
  // t=30: A buf0 + b0; load B(31); no stage; full drain
  LOADB(b1, 31);
  MFMA_STEP(0, b0);
  ENDSTEP(0)
  // t=31: A buf1 + b1
  MFMA_STEP(1, b1);

  // ---- epilogue: C/D layout col=lane&15, row=(lane>>4)*4+j ----
#pragma unroll
  for (int m = 0; m < 4; ++m)
#pragma unroll
    for (int n = 0; n < 4; ++n)
#pragma unroll
      for (int j = 0; j < 4; ++j) {
        float v = acc[m][n][j];
        size_t idx = (size_t)(bm + wr + m * 16 + kq * 4 + j) * C_DIM + (bn + wc + n * 16 + fr);
        if (mode == 0) {
          outK[idx] = f2bf(__expf(fminf(v, 60.f)));
        } else if (mode == 1) {
          outV[idx] = f2bf(v);
        } else {
          outR[idx] = f2bf(1.f / (1.f + __expf(-v)));
        }
      }
#undef BODY
#undef ENDSTEP
#undef MFMA_STEP
#undef LOADB
}

// ============ output GEMM: 128x128 tile, BK=64, 2-phase (R6 form) ==========
__global__ __launch_bounds__(256, 2) void gemm_out(const ushort_t* __restrict__ A,
                                                   const ushort_t* __restrict__ Bw,
                                                   float* __restrict__ outF) {
  constexpr int K = 1024;
  constexpr int NT = K / 64;
  __shared__ ushort_t As[2][128 * 64];
  __shared__ ushort_t Bs[2][128 * 64];

  const int tid = threadIdx.x;
  const int l = tid & 63;
  const int wave = tid >> 6;
  const int fr = l & 15;
  const int kq = l >> 4;

  const int bid = blockIdx.x;
  const int xcd = bid & 7;
  const int idx = bid >> 3;
  const int jb = idx >> 3;
  const int bm = (xcd * 8 + (idx & 7)) * 128;
  const int bn = jb * 128;

  const int wr = (wave >> 1) * 64;
  const int wc = (wave & 1) * 64;

  f32x4 acc[4][4];
#pragma unroll
  for (int m = 0; m < 4; ++m)
#pragma unroll
    for (int n = 0; n < 4; ++n) acc[m][n] = (f32x4){0.f, 0.f, 0.f, 0.f};

  int srow[4], scol[4];
#pragma unroll
  for (int j = 0; j < 4; ++j) {
    int row = wave * 32 + j * 8 + (l >> 3);
    srow[j] = row;
    scol[j] = ((l & 7) ^ (row & 7)) * 8;
  }
  const ushort_t* AgB = A + (size_t)bm * K;
  const ushort_t* BgB = Bw + (size_t)bn * K;
  const int dst0 = wave * 2048 + l * 8;

  auto stage = [&](int buf, int k0) {
#pragma unroll
    for (int j = 0; j < 4; ++j)
      gload_lds16(AgB + (size_t)srow[j] * K + scol[j] + k0, &As[buf][dst0 + j * 512]);
#pragma unroll
    for (int j = 0; j < 4; ++j)
      gload_lds16(BgB + (size_t)srow[j] * K + scol[j] + k0, &Bs[buf][dst0 + j * 512]);
  };

  stage(0, 0);
  asm volatile("s_waitcnt vmcnt(0)" ::: "memory");
  __syncthreads();

  const int ps0 = ((0 * 4 + kq) ^ (fr & 7)) * 8;
  const int ps1 = ((1 * 4 + kq) ^ (fr & 7)) * 8;

  int cur = 0;
  for (int t = 0; t < NT; ++t) {
    if (t < NT - 1) stage(cur ^ 1, (t + 1) * 64);
    short8 af[4][2], bfr[4][2];
#pragma unroll
    for (int m = 0; m < 4; ++m) {
      af[m][0] = *(const short8*)&As[cur][(wr + m * 16 + fr) * 64 + ps0];
      af[m][1] = *(const short8*)&As[cur][(wr + m * 16 + fr) * 64 + ps1];
    }
#pragma unroll
    for (int n = 0; n < 4; ++n) {
      bfr[n][0] = *(const short8*)&Bs[cur][(wc + n * 16 + fr) * 64 + ps0];
      bfr[n][1] = *(const short8*)&Bs[cur][(wc + n * 16 + fr) * 64 + ps1];
    }
#pragma unroll
    for (int m = 0; m < 4; ++m)
#pragma unroll
      for (int n = 0; n < 4; ++n)
#pragma unroll
        for (int ks = 0; ks < 2; ++ks)
          acc[m][n] = __builtin_amdgcn_mfma_f32_16x16x32_bf16(af[m][ks], bfr[n][ks], acc[m][n], 0, 0, 0);
    asm volatile("s_waitcnt vmcnt(0)" ::: "memory");
    __syncthreads();
    cur ^= 1;
  }

#pragma unroll
  for (int m = 0; m < 4; ++m)
#pragma unroll
    for (int n = 0; n < 4; ++n)
#pragma unroll
      for (int j = 0; j < 4; ++j)
        outF[(size_t)(bm + wr + m * 16 + kq * 4 + j) * C_DIM + (bn + wc + n * 16 + fr)] =
            acc[m][n][j];
}

// ---------------- wkv chunked scan -----------------------------------------
__global__ void wkv_phaseA(const ushort_t* __restrict__ kk, const ushort_t* __restrict__ vv,
                           const float* __restrict__ td,
                           float* __restrict__ sa, float* __restrict__ sb,
                           float* __restrict__ sp) {
  int gid = blockIdx.x * 256 + threadIdx.x;
  int c = gid & (C_DIM - 1);
  int ch = (gid >> 10) & (NCH - 1);
  int b = gid >> 15;
  float w = td[c] * (1.f / T_LEN);
  size_t base = ((size_t)b * T_LEN + ch * CHL) * C_DIM + c;
  float a = 0.f, bb = 0.f, p = -1e38f;
  for (int t = 0; t < CHL; ++t) {
    float kt = bf2f(kk[base + (size_t)t * C_DIM]);
    float vt = bf2f(vv[base + (size_t)t * C_DIM]);
    float no2 = fmaxf(w + p, kt);
    float e1 = __expf(w + p - no2);
    float e2 = __expf(kt - no2);
    a = e1 * a + e2 * vt;
    bb = e1 * bb + e2;
    p = no2;
  }
  sa[gid] = a; sb[gid] = bb; sp[gid] = p;
}

__global__ void wkv_phaseC2(const ushort_t* __restrict__ kk, const ushort_t* __restrict__ vv,
                            const ushort_t* __restrict__ sr, const float* __restrict__ td,
                            const float* __restrict__ tf,
                            const float* __restrict__ sa, const float* __restrict__ sb,
                            const float* __restrict__ sp, ushort_t* __restrict__ sy) {
  int gid = blockIdx.x * 256 + threadIdx.x;
  int c = gid & (C_DIM - 1);
  int ch = (gid >> 10) & (NCH - 1);
  int b = gid >> 15;
  float w = td[c] * (1.f / T_LEN);
  float u = tf[c] * (1.f / T_LEN);
  float wL = w * (float)CHL;

  float a = 0.f, bb = 0.f, p = -1e38f;
  size_t sbase = ((size_t)b * NCH) * C_DIM + c;
  for (int j = 0; j < ch; ++j) {
    float ac = sa[sbase + (size_t)j * C_DIM];
    float bc = sb[sbase + (size_t)j * C_DIM];
    float pc = sp[sbase + (size_t)j * C_DIM];
    float pn = fmaxf(p + wL, pc);
    float e1 = __expf(p + wL - pn);
    float e2 = __expf(pc - pn);
    a = e1 * a + e2 * ac;
    bb = e1 * bb + e2 * bc;
    p = pn;
  }

  size_t base = ((size_t)b * T_LEN + ch * CHL) * C_DIM + c;
  for (int t = 0; t < CHL; ++t) {
    float kt = bf2f(kk[base + (size_t)t * C_DIM]);
    float vt = bf2f(vv[base + (size_t)t * C_DIM]);
    float no = fmaxf(p, u + kt);
    float e1 = __expf(p - no);
    float e2 = __expf(u + kt - no);
    float y = (e1 * a + e2 * vt) / (e1 * bb + e2);
    float srv = bf2f(sr[base + (size_t)t * C_DIM]);
    sy[base + (size_t)t * C_DIM] = f2bf(srv * y);
    float no2 = fmaxf(w + p, kt);
    e1 = __expf(w + p - no2);
    e2 = __expf(kt - no2);
    a = e1 * a + e2 * vt;
    bb = e1 * bb + e2;
    p = no2;
  }
}

// ---------------------------------------------------------------------------
extern "C" void kernel_launch(void* const* d_in, const int* in_sizes, int n_in,
                              void* d_out, int out_size, void* d_ws, size_t ws_size,
                              hipStream_t stream) {
  const float* x  = (const float*)d_in[0];
  const float* td = (const float*)d_in[1];
  const float* tf = (const float*)d_in[2];
  const float* tm = (const float*)d_in[3];
  const float* cm = (const float*)d_in[4];
  const float* Wk = (const float*)d_in[5];
  const float* Wv = (const float*)d_in[6];
  const float* Wr = (const float*)d_in[7];
  const float* Wo = (const float*)d_in[8];

  const size_t MC = (size_t)M_ROWS * C_DIM;
  const size_t CC = (size_t)C_DIM * C_DIM;

  char* ws = (char*)d_ws;
  ushort_t* xmb = (ushort_t*)ws; ws += MC * 2;
  ushort_t* Wob = (ushort_t*)ws; ws += CC * 2;        // Wo row-major bf16
  ushort_t* Wfr = (ushort_t*)ws; ws += 3 * CC * 2;    // Wk/v/r fragment-major
  ushort_t* kk  = (ushort_t*)ws; ws += MC * 2;
  ushort_t* vv  = (ushort_t*)ws; ws += MC * 2;
  ushort_t* sr  = (ushort_t*)ws; ws += MC * 2;
  ushort_t* sy  = (ushort_t*)ws; ws += MC * 2;
  float* sa = (float*)ws; ws += (size_t)B_SZ * NCH * C_DIM * 4;
  float* sb = (float*)ws; ws += (size_t)B_SZ * NCH * C_DIM * 4;
  float* sp = (float*)ws; ws += (size_t)B_SZ * NCH * C_DIM * 4;

  prep_kernel<<<dim3(10752), 256, 0, stream>>>(Wk, Wv, Wr, Wo, Wob, Wfr, x, tm, cm, xmb);

  // fused k/v/r projections: 1536 blocks, A 3-buf LDS + B frag-major regs
  gemm_fused<<<dim3(1536), 256, 0, stream>>>(xmb, Wfr, kk, vv, sr);

  wkv_phaseA<<<(B_SZ * NCH * C_DIM) / 256, 256, 0, stream>>>(kk, vv, td, sa, sb, sp);
  wkv_phaseC2<<<(B_SZ * NCH * C_DIM) / 256, 256, 0, stream>>>(kk, vv, sr, td, tf, sa, sb, sp, sy);

  // output projection: 512 blocks, XCD-swizzled
  gemm_out<<<dim3(512), 256, 0, stream>>>(sy, Wob, (float*)d_out);
}